// Round 1
// baseline (16280.771 us; speedup 1.0000x reference)
//
#include <hip/hip_runtime.h>
#include <cstdint>
#include <cstddef>

#define NV 50257
#define ND 1024
#define NT 1024
#define NH 16
#define NL 6
#define NB 2
#define NHS 64
#define NM 2048   // B*T
#define NF 4096   // 4*D
#define EPSLN 1e-5f

__device__ __forceinline__ float wave_reduce_sum(float v) {
#pragma unroll
    for (int off = 32; off >= 1; off >>= 1) v += __shfl_xor(v, off, 64);
    return v;
}

// ---------------- embedding: x[m,:] = tok_emb[idx[m],:] + pos_emb[t,:] ----------------
__global__ __launch_bounds__(256) void k_embed(const int* __restrict__ idx,
                                               const float* __restrict__ tok,
                                               const float* __restrict__ pos,
                                               float* __restrict__ x) {
    int m = blockIdx.x;          // 0..NM-1
    int t = m & (NT - 1);
    int tokid = idx[m];
    int d = threadIdx.x * 4;
    float4 a = *(const float4*)(tok + (size_t)tokid * ND + d);
    float4 p = *(const float4*)(pos + (size_t)t * ND + d);
    a.x += p.x; a.y += p.y; a.z += p.z; a.w += p.w;
    *(float4*)(x + (size_t)m * ND + d) = a;
}

// ---------------- layernorm over last dim (D=1024), one block per row ----------------
__global__ __launch_bounds__(256) void k_layernorm(const float* __restrict__ x,
                                                   const float* __restrict__ g,
                                                   const float* __restrict__ b,
                                                   float* __restrict__ out) {
    int m = blockIdx.x;
    int d = threadIdx.x * 4;
    const float4 v = *(const float4*)(x + (size_t)m * ND + d);
    float s = v.x + v.y + v.z + v.w;
    float q = v.x * v.x + v.y * v.y + v.z * v.z + v.w * v.w;
    s = wave_reduce_sum(s);
    q = wave_reduce_sum(q);
    __shared__ float ss[4], sq[4];
    int lane = threadIdx.x & 63, w = threadIdx.x >> 6;
    if (lane == 0) { ss[w] = s; sq[w] = q; }
    __syncthreads();
    s = ss[0] + ss[1] + ss[2] + ss[3];
    q = sq[0] + sq[1] + sq[2] + sq[3];
    float mu = s * (1.0f / ND);
    float var = q * (1.0f / ND) - mu * mu;
    float rstd = rsqrtf(var + EPSLN);
    float4 gg = *(const float4*)(g + d);
    float4 bb = *(const float4*)(b + d);
    float4 o;
    o.x = (v.x - mu) * rstd * gg.x + bb.x;
    o.y = (v.y - mu) * rstd * gg.y + bb.y;
    o.z = (v.z - mu) * rstd * gg.z + bb.z;
    o.w = (v.w - mu) * rstd * gg.w + bb.w;
    *(float4*)(out + (size_t)m * ND + d) = o;
}

// ---------------- tiled f32 GEMM: C[M,N] = A[M,K] @ B[K,N] (+bias)(relu)(+resid) ------
// 64x64 tile, BK=16, 256 threads, 4x4 per thread.
// headStride != 0: B tile for n-block bx is at Bm + bx*headStride, ldb local (QKV).
template <bool RELU, bool RESID, bool NBOUND>
__global__ __launch_bounds__(256) void k_gemm(const float* __restrict__ A, int lda,
                                              const float* __restrict__ Bm, int ldb,
                                              long long headStride,
                                              const float* __restrict__ bias,
                                              const float* __restrict__ resid,
                                              float* __restrict__ C, int ldc,
                                              int N, int K) {
    __shared__ float As[16][68];   // padded: write conflicts -> 2-way (free)
    __shared__ float Bs[16][64];
    const int bx = blockIdx.x, by = blockIdx.y;
    const int n0 = bx * 64, m0 = by * 64;
    const int tid = threadIdx.x;
    const int tx = tid & 15, ty = tid >> 4;
    const float* Bt = headStride ? (Bm + (size_t)bx * (size_t)headStride) : (Bm + n0);
    const int arow = tid >> 2;          // 0..63
    const int akq = (tid & 3) << 2;     // 0,4,8,12
    const int brow = tid >> 4;          // 0..15
    const int bnq = (tid & 15) << 2;    // 0..60
    float acc[4][4] = {};
    for (int k0 = 0; k0 < K; k0 += 16) {
        float4 a = *(const float4*)(A + (size_t)(m0 + arow) * lda + k0 + akq);
        As[akq + 0][arow] = a.x;
        As[akq + 1][arow] = a.y;
        As[akq + 2][arow] = a.z;
        As[akq + 3][arow] = a.w;
        const float* bp = Bt + (size_t)(k0 + brow) * ldb + bnq;
        if (!NBOUND) {
            *(float4*)&Bs[brow][bnq] = *(const float4*)bp;
        } else {
#pragma unroll
            for (int i = 0; i < 4; ++i)
                Bs[brow][bnq + i] = (n0 + bnq + i < N) ? bp[i] : 0.f;
        }
        __syncthreads();
#pragma unroll
        for (int kk = 0; kk < 16; ++kk) {
            const float4 av = *(const float4*)&As[kk][ty << 2];
            const float4 bv = *(const float4*)&Bs[kk][tx << 2];
            acc[0][0] = fmaf(av.x, bv.x, acc[0][0]);
            acc[0][1] = fmaf(av.x, bv.y, acc[0][1]);
            acc[0][2] = fmaf(av.x, bv.z, acc[0][2]);
            acc[0][3] = fmaf(av.x, bv.w, acc[0][3]);
            acc[1][0] = fmaf(av.y, bv.x, acc[1][0]);
            acc[1][1] = fmaf(av.y, bv.y, acc[1][1]);
            acc[1][2] = fmaf(av.y, bv.z, acc[1][2]);
            acc[1][3] = fmaf(av.y, bv.w, acc[1][3]);
            acc[2][0] = fmaf(av.z, bv.x, acc[2][0]);
            acc[2][1] = fmaf(av.z, bv.y, acc[2][1]);
            acc[2][2] = fmaf(av.z, bv.z, acc[2][2]);
            acc[2][3] = fmaf(av.z, bv.w, acc[2][3]);
            acc[3][0] = fmaf(av.w, bv.x, acc[3][0]);
            acc[3][1] = fmaf(av.w, bv.y, acc[3][1]);
            acc[3][2] = fmaf(av.w, bv.z, acc[3][2]);
            acc[3][3] = fmaf(av.w, bv.w, acc[3][3]);
        }
        __syncthreads();
    }
#pragma unroll
    for (int i = 0; i < 4; ++i) {
        const int mrow = m0 + (ty << 2) + i;
#pragma unroll
        for (int j = 0; j < 4; ++j) {
            const int n = n0 + (tx << 2) + j;
            if (NBOUND && n >= N) continue;
            float c = acc[i][j];
            if (bias) c += bias[n];
            if (RELU) c = fmaxf(c, 0.f);
            if (RESID) c += resid[(size_t)mrow * ldc + n];
            C[(size_t)mrow * ldc + n] = c;
        }
    }
}

// ---------------- causal attention, one wave per (b,h,t) query row --------------------
// q,k,v,o layout: [B,T,H*HS] (= [m, h*64+i]); lane i owns dim i of the head.
__global__ __launch_bounds__(64) void k_attn(const float* __restrict__ q,
                                             const float* __restrict__ k,
                                             const float* __restrict__ v,
                                             float* __restrict__ o) {
    int bid = blockIdx.x;            // b*H*T + h*T + t? no: bid = ((b*16+h)<<10)|t
    int t = bid & (NT - 1);
    int bh = bid >> 10;
    int b = bh >> 4, h = bh & 15;
    int lane = threadIdx.x;
    size_t qoff = (size_t)(b * NT + t) * ND + h * NHS;
    float qi = q[qoff + lane];
    size_t kvbase = (size_t)(b * NT) * ND + h * NHS + lane;
    float m = -INFINITY, l = 0.f, oi = 0.f;
    for (int s = 0; s <= t; ++s) {
        float ki = k[kvbase + (size_t)s * ND];
        float dot = wave_reduce_sum(qi * ki);
        float score = dot * 0.125f;   // HS^-0.5
        float mn = fmaxf(m, score);
        float sc = __expf(m - mn);    // exp(-inf)=0 on first iter
        float p = __expf(score - mn);
        float vi = v[kvbase + (size_t)s * ND];
        l = l * sc + p;
        oi = oi * sc + p * vi;
        m = mn;
    }
    o[qoff + lane] = oi / l;
}

// ---------------- per-row loss: lse - logit[target], one block per row ----------------
__global__ __launch_bounds__(256) void k_rowloss(const float* __restrict__ logits,
                                                 const int* __restrict__ targets,
                                                 float* __restrict__ rl) {
    int m = blockIdx.x;
    const float* row = logits + (size_t)m * NV;
    int tid = threadIdx.x;
    int lane = tid & 63, w = tid >> 6;
    float mx = -INFINITY;
    for (int j = tid; j < NV; j += 256) mx = fmaxf(mx, row[j]);
#pragma unroll
    for (int off = 32; off >= 1; off >>= 1) mx = fmaxf(mx, __shfl_xor(mx, off, 64));
    __shared__ float sm[4];
    if (lane == 0) sm[w] = mx;
    __syncthreads();
    mx = fmaxf(fmaxf(sm[0], sm[1]), fmaxf(sm[2], sm[3]));
    float s = 0.f;
    for (int j = tid; j < NV; j += 256) s += __expf(row[j] - mx);
    s = wave_reduce_sum(s);
    __shared__ float sv[4];
    if (lane == 0) sv[w] = s;
    __syncthreads();
    s = sv[0] + sv[1] + sv[2] + sv[3];
    if (tid == 0) {
        float lse = logf(s) + mx;
        rl[m] = lse - row[targets[m]];
    }
}

__global__ __launch_bounds__(256) void k_lossreduce(const float* __restrict__ rl,
                                                    float* __restrict__ out_loss) {
    int tid = threadIdx.x;
    float s = 0.f;
    for (int j = tid; j < NM; j += 256) s += rl[j];
    s = wave_reduce_sum(s);
    __shared__ float sv[4];
    int lane = tid & 63, w = tid >> 6;
    if (lane == 0) sv[w] = s;
    __syncthreads();
    if (tid == 0) out_loss[0] = (sv[0] + sv[1] + sv[2] + sv[3]) * (1.0f / NM);
}

extern "C" void kernel_launch(void* const* d_in, const int* in_sizes, int n_in,
                              void* d_out, int out_size, void* d_ws, size_t ws_size,
                              hipStream_t stream) {
    const int* idx      = (const int*)d_in[0];
    const int* targets  = (const int*)d_in[1];
    const float* tok    = (const float*)d_in[2];
    const float* pos    = (const float*)d_in[3];
    const float* wq     = (const float*)d_in[4];
    const float* wk     = (const float*)d_in[5];
    const float* wv     = (const float*)d_in[6];
    const float* wproj  = (const float*)d_in[7];
    const float* bproj  = (const float*)d_in[8];
    const float* ln1_g  = (const float*)d_in[9];
    const float* ln1_b  = (const float*)d_in[10];
    const float* ln2_g  = (const float*)d_in[11];
    const float* ln2_b  = (const float*)d_in[12];
    const float* w1     = (const float*)d_in[13];
    const float* b1     = (const float*)d_in[14];
    const float* w2     = (const float*)d_in[15];
    const float* b2     = (const float*)d_in[16];
    const float* lnf_g  = (const float*)d_in[17];
    const float* lnf_b  = (const float*)d_in[18];
    const float* lm_w   = (const float*)d_in[19];
    const float* lm_b   = (const float*)d_in[20];
    float* out = (float*)d_out;

    float* ws = (float*)d_ws;
    const size_t SZ = (size_t)NM * ND;   // 2M floats
    float* x   = ws;
    float* h   = x + SZ;
    float* qb  = h + SZ;
    float* kb  = qb + SZ;
    float* vb  = kb + SZ;
    float* ob  = vb + SZ;
    float* hid = ob + SZ;                 // NM*NF
    float* rl  = hid + (size_t)NM * NF;   // NM floats

    const long long HSTRIDE = (long long)ND * NHS;  // 65536: per-head weight block

    k_embed<<<NM, 256, 0, stream>>>(idx, tok, pos, x);

    for (int l = 0; l < NL; ++l) {
        const float* wq_l = wq + (size_t)l * NH * ND * NHS;
        const float* wk_l = wk + (size_t)l * NH * ND * NHS;
        const float* wv_l = wv + (size_t)l * NH * ND * NHS;
        const float* wp_l = wproj + (size_t)l * ND * ND;
        const float* bp_l = bproj + (size_t)l * ND;
        const float* w1_l = w1 + (size_t)l * ND * NF;
        const float* b1_l = b1 + (size_t)l * NF;
        const float* w2_l = w2 + (size_t)l * NF * ND;
        const float* b2_l = b2 + (size_t)l * ND;

        k_layernorm<<<NM, 256, 0, stream>>>(x, ln1_g + (size_t)l * ND, ln1_b + (size_t)l * ND, h);

        dim3 gqkv(NH, NM / 64);  // 16 head-tiles x 32 m-tiles
        k_gemm<false, false, false><<<gqkv, 256, 0, stream>>>(h, ND, wq_l, NHS, HSTRIDE,
                                                              nullptr, nullptr, qb, ND, ND, ND);
        k_gemm<false, false, false><<<gqkv, 256, 0, stream>>>(h, ND, wk_l, NHS, HSTRIDE,
                                                              nullptr, nullptr, kb, ND, ND, ND);
        k_gemm<false, false, false><<<gqkv, 256, 0, stream>>>(h, ND, wv_l, NHS, HSTRIDE,
                                                              nullptr, nullptr, vb, ND, ND, ND);

        k_attn<<<NB * NH * NT, 64, 0, stream>>>(qb, kb, vb, ob);

        dim3 gproj(ND / 64, NM / 64);
        k_gemm<false, true, false><<<gproj, 256, 0, stream>>>(ob, ND, wp_l, ND, 0,
                                                              bp_l, x, x, ND, ND, ND);

        k_layernorm<<<NM, 256, 0, stream>>>(x, ln2_g + (size_t)l * ND, ln2_b + (size_t)l * ND, h);

        dim3 gmlp1(NF / 64, NM / 64);
        k_gemm<true, false, false><<<gmlp1, 256, 0, stream>>>(h, ND, w1_l, NF, 0,
                                                              b1_l, nullptr, hid, NF, NF, ND);
        dim3 gmlp2(ND / 64, NM / 64);
        k_gemm<false, true, false><<<gmlp2, 256, 0, stream>>>(hid, NF, w2_l, ND, 0,
                                                              b2_l, x, x, ND, ND, NF);
    }

    k_layernorm<<<NM, 256, 0, stream>>>(x, lnf_g, lnf_b, h);

    dim3 glm((NV + 63) / 64, NM / 64);
    k_gemm<false, false, true><<<glm, 256, 0, stream>>>(h, ND, lm_w, NV, 0,
                                                        lm_b, nullptr, out, NV, NV, ND);

    k_rowloss<<<NM, 256, 0, stream>>>(out, targets, rl);
    k_lossreduce<<<1, 256, 0, stream>>>(rl, out + (size_t)NM * NV);
}

// Round 2
// 2749.565 us; speedup vs baseline: 5.9212x; 5.9212x over previous
//
#include <hip/hip_runtime.h>
#include <cstdint>
#include <cstddef>

typedef unsigned short u16;
typedef __bf16 bf16x8 __attribute__((ext_vector_type(8)));
typedef float f32x4 __attribute__((ext_vector_type(4)));
typedef short short8_t __attribute__((ext_vector_type(8)));

#define NV 50257
#define NVPAD 50304   // 393 * 128
#define ND 1024
#define NT 1024
#define NH 16
#define NL 6
#define NB 2
#define NM 2048       // B*T
#define NF 4096       // 4*D
#define EPSLN 1e-5f

__device__ __forceinline__ u16 f2bf(float f) {
    unsigned u = __float_as_uint(f);
    return (u16)((u + 0x7fffu + ((u >> 16) & 1u)) >> 16);   // RNE
}
__device__ __forceinline__ float bf2f(u16 h) {
    return __uint_as_float(((unsigned)h) << 16);
}

__device__ __forceinline__ float wave_reduce_sum(float v) {
#pragma unroll
    for (int off = 32; off >= 1; off >>= 1) v += __shfl_xor(v, off, 64);
    return v;
}

// ---------------- embedding: x[m,:] = tok_emb[idx[m],:] + pos_emb[t,:] ----------------
__global__ __launch_bounds__(256) void k_embed(const int* __restrict__ idx,
                                               const float* __restrict__ tok,
                                               const float* __restrict__ pos,
                                               float* __restrict__ x) {
    int m = blockIdx.x;
    int t = m & (NT - 1);
    int tokid = idx[m];
    int d = threadIdx.x * 4;
    float4 a = *(const float4*)(tok + (size_t)tokid * ND + d);
    float4 p = *(const float4*)(pos + (size_t)t * ND + d);
    a.x += p.x; a.y += p.y; a.z += p.z; a.w += p.w;
    *(float4*)(x + (size_t)m * ND + d) = a;
}

// ---------------- layernorm over last dim (D=1024), one block per row ----------------
template <bool OUTBF16>
__global__ __launch_bounds__(256) void k_layernorm(const float* __restrict__ x,
                                                   const float* __restrict__ g,
                                                   const float* __restrict__ b,
                                                   float* __restrict__ outf,
                                                   u16* __restrict__ outb) {
    int m = blockIdx.x;
    int d = threadIdx.x * 4;
    const float4 v = *(const float4*)(x + (size_t)m * ND + d);
    float s = v.x + v.y + v.z + v.w;
    float q = v.x * v.x + v.y * v.y + v.z * v.z + v.w * v.w;
    s = wave_reduce_sum(s);
    q = wave_reduce_sum(q);
    __shared__ float ss[4], sq[4];
    int lane = threadIdx.x & 63, w = threadIdx.x >> 6;
    if (lane == 0) { ss[w] = s; sq[w] = q; }
    __syncthreads();
    s = ss[0] + ss[1] + ss[2] + ss[3];
    q = sq[0] + sq[1] + sq[2] + sq[3];
    float mu = s * (1.0f / ND);
    float var = q * (1.0f / ND) - mu * mu;
    float rstd = rsqrtf(var + EPSLN);
    float4 gg = *(const float4*)(g + d);
    float4 bb = *(const float4*)(b + d);
    float o0 = (v.x - mu) * rstd * gg.x + bb.x;
    float o1 = (v.y - mu) * rstd * gg.y + bb.y;
    float o2 = (v.z - mu) * rstd * gg.z + bb.z;
    float o3 = (v.w - mu) * rstd * gg.w + bb.w;
    if (OUTBF16) {
        ushort4 pk;
        pk.x = f2bf(o0); pk.y = f2bf(o1); pk.z = f2bf(o2); pk.w = f2bf(o3);
        *(ushort4*)(outb + (size_t)m * ND + d) = pk;
    } else {
        float4 o; o.x = o0; o.y = o1; o.z = o2; o.w = o3;
        *(float4*)(outf + (size_t)m * ND + d) = o;
    }
}

// ---------------- weight transpose + f32->bf16: Wt[n][k] = W[..k..n..] ----------------
// src element for (k, n): head = n / hs, nc = n % hs, at W[head*K*hs + k*ld + nc].
// (standard weights: hs = N, ld = N, head = 0; QKV per-head: hs = 64, ld = 64)
__global__ __launch_bounds__(256) void k_wtrans(const float* __restrict__ W,
                                                u16* __restrict__ Wt,
                                                int K, int N, int Npad, int hs, int ld) {
    __shared__ float t[32][33];
    const int nb = blockIdx.x << 5, kb = blockIdx.y << 5;
    const int tx = threadIdx.x & 31, tq = threadIdx.x >> 5;   // tq 0..7
    const int n = nb + tx;
    if (n < N) {
        const int head = n / hs, nc = n - head * hs;
        const float* src = W + (size_t)head * K * hs + nc;
#pragma unroll
        for (int i = 0; i < 4; ++i)
            t[(tq << 2) + i][tx] = src[(size_t)(kb + (tq << 2) + i) * ld];
    } else {
#pragma unroll
        for (int i = 0; i < 4; ++i) t[(tq << 2) + i][tx] = 0.f;
    }
    __syncthreads();
#pragma unroll
    for (int i = 0; i < 4; ++i) {
        const int nn = nb + (tq << 2) + i;
        if (nn < Npad) Wt[(size_t)nn * K + kb + tx] = f2bf(t[tx][(tq << 2) + i]);
    }
}

// ---------------- bf16 MFMA GEMM: C[M,N] = A[M,K] * Bt[N,K]^T  (m97-style) ------------
// 128x128 tile, BK=32, 256 threads = 4 waves (2x2), each wave 64x64 = 4x4 frags 16x16x32.
template <bool RELU, bool RESID, bool NBOUND, bool OUTBF16>
__global__ __launch_bounds__(256) void k_mfma_gemm(
    const u16* __restrict__ A, const u16* __restrict__ Bt,
    const float* __restrict__ bias, const float* __restrict__ resid,
    float* __restrict__ Cf, u16* __restrict__ Cb,
    int K, int N, int ldc)
{
    __shared__ u16 As[128 * 32];
    __shared__ u16 Bs[128 * 32];
    const int n0 = blockIdx.x * 128, m0 = blockIdx.y * 128;
    const int tid = threadIdx.x;
    const int lane = tid & 63, wv = tid >> 6;
    const int wr = wv >> 1, wc = wv & 1;
    const int lr = lane & 15, kg = lane >> 4;
    const int srow = tid >> 2, scol = (tid & 3) << 3;

    const u16* Ag0 = A + (size_t)(m0 + srow) * K + scol;
    const u16* Ag1 = Ag0 + (size_t)64 * K;
    const u16* Bg0 = Bt + (size_t)(n0 + srow) * K + scol;
    const u16* Bg1 = Bg0 + (size_t)64 * K;
    u16* AsW0 = &As[srow * 32 + scol];
    u16* AsW1 = &As[(64 + srow) * 32 + scol];
    u16* BsW0 = &Bs[srow * 32 + scol];
    u16* BsW1 = &Bs[(64 + srow) * 32 + scol];

    const u16* Ar0 = &As[(wr * 64 + lr) * 32 + kg * 8];
    const u16* Br0 = &Bs[(wc * 64 + lr) * 32 + kg * 8];

    f32x4 acc[4][4] = {};
    short8_t ra0 = *(const short8_t*)Ag0;
    short8_t ra1 = *(const short8_t*)Ag1;
    short8_t rb0 = *(const short8_t*)Bg0;
    short8_t rb1 = *(const short8_t*)Bg1;
    for (int k0 = 0; k0 < K; k0 += 32) {
        __syncthreads();
        *(short8_t*)AsW0 = ra0;
        *(short8_t*)AsW1 = ra1;
        *(short8_t*)BsW0 = rb0;
        *(short8_t*)BsW1 = rb1;
        __syncthreads();
        if (k0 + 32 < K) {               // prefetch next K-step (overlaps MFMA)
            ra0 = *(const short8_t*)(Ag0 + k0 + 32);
            ra1 = *(const short8_t*)(Ag1 + k0 + 32);
            rb0 = *(const short8_t*)(Bg0 + k0 + 32);
            rb1 = *(const short8_t*)(Bg1 + k0 + 32);
        }
        bf16x8 af[4], bfr[4];
#pragma unroll
        for (int mi = 0; mi < 4; ++mi) af[mi] = *(const bf16x8*)(Ar0 + mi * 16 * 32);
#pragma unroll
        for (int ni = 0; ni < 4; ++ni) bfr[ni] = *(const bf16x8*)(Br0 + ni * 16 * 32);
#pragma unroll
        for (int mi = 0; mi < 4; ++mi)
#pragma unroll
            for (int ni = 0; ni < 4; ++ni)
                acc[mi][ni] = __builtin_amdgcn_mfma_f32_16x16x32_bf16(af[mi], bfr[ni], acc[mi][ni], 0, 0, 0);
    }
    // epilogue: C/D layout col = lane&15, row = (lane>>4)*4 + r   [m89/m91-verified]
#pragma unroll
    for (int mi = 0; mi < 4; ++mi) {
#pragma unroll
        for (int ni = 0; ni < 4; ++ni) {
#pragma unroll
            for (int r = 0; r < 4; ++r) {
                const int row = m0 + wr * 64 + mi * 16 + kg * 4 + r;
                const int col = n0 + wc * 64 + ni * 16 + lr;
                if (NBOUND && col >= N) continue;
                float c = acc[mi][ni][r];
                if (bias) c += bias[col];
                if (RELU) c = fmaxf(c, 0.f);
                if (RESID) c += resid[(size_t)row * ldc + col];
                if (OUTBF16) Cb[(size_t)row * ldc + col] = f2bf(c);
                else         Cf[(size_t)row * ldc + col] = c;
            }
        }
    }
}

// ---------------- flash attention: 64q x 64s f32 tiles, online softmax ----------------
// qkv: [NM][3072] bf16 (q | k | v each ND wide); block = (q-tile, b*H+h), 256 threads.
__global__ __launch_bounds__(256) void k_attn_flash(const u16* __restrict__ qkv,
                                                    u16* __restrict__ ob) {
    const int qt = blockIdx.x, bh = blockIdx.y;
    const int b = bh >> 4, h = bh & 15;
    const int q0 = qt * 64;
    const int tid = threadIdx.x;
    const int tx = tid & 15, ty = tid >> 4;
    const int wvi = tid >> 6;
    const int ROWS = 3 * ND;

    __shared__ float Qt[64][68];   // [d][q]
    __shared__ float Kt[64][68];   // [d][s]
    __shared__ float Vs[64][68];   // [s][d]
    __shared__ float Pt[64][68];   // [s][q]
    __shared__ float red[4][64];
    __shared__ float red2[4][64];
    __shared__ float mstate[64], lstate[64], rfac[64], mnew_s[64];

    {   // stage Q transposed
        const int qq = tid >> 2, dblk = (tid & 3) << 4;
        const u16* src = qkv + (size_t)(b * NT + q0 + qq) * ROWS + h * 64 + dblk;
        short8_t v0 = *(const short8_t*)src;
        short8_t v1 = *(const short8_t*)(src + 8);
#pragma unroll
        for (int j = 0; j < 8; ++j) { Qt[dblk + j][qq] = bf2f((u16)v0[j]); Qt[dblk + 8 + j][qq] = bf2f((u16)v1[j]); }
    }
    if (tid < 64) { mstate[tid] = -3.0e38f; lstate[tid] = 0.f; }

    float acc_o[4][4] = {};   // q = ty*4+i, d = tx*4+j
    for (int st = 0; st <= qt; ++st) {
        __syncthreads();   // protect Kt/Vs/Pt from previous iteration readers
        {   // stage K transposed + V natural
            const int ss = tid >> 2, dblk = (tid & 3) << 4;
            const u16* ksrc = qkv + (size_t)(b * NT + st * 64 + ss) * ROWS + ND + h * 64 + dblk;
            const u16* vsrc = ksrc + ND;
            short8_t k0 = *(const short8_t*)ksrc;
            short8_t k1 = *(const short8_t*)(ksrc + 8);
            short8_t w0 = *(const short8_t*)vsrc;
            short8_t w1 = *(const short8_t*)(vsrc + 8);
#pragma unroll
            for (int j = 0; j < 8; ++j) { Kt[dblk + j][ss] = bf2f((u16)k0[j]); Kt[dblk + 8 + j][ss] = bf2f((u16)k1[j]); }
#pragma unroll
            for (int j = 0; j < 8; ++j) { Vs[ss][dblk + j] = bf2f((u16)w0[j]); Vs[ss][dblk + 8 + j] = bf2f((u16)w1[j]); }
        }
        __syncthreads();
        // S^T[s][q]: s = ty*4+i, q = tx*4+j
        float accs[4][4] = {};
#pragma unroll 8
        for (int dd = 0; dd < 64; ++dd) {
            const f32x4 av = *(const f32x4*)&Kt[dd][ty << 2];
            const f32x4 bv = *(const f32x4*)&Qt[dd][tx << 2];
#pragma unroll
            for (int i = 0; i < 4; ++i)
#pragma unroll
                for (int j = 0; j < 4; ++j) accs[i][j] = fmaf(av[i], bv[j], accs[i][j]);
        }
        const int sloc = ty << 2, qloc = tx << 2;
#pragma unroll
        for (int i = 0; i < 4; ++i)
#pragma unroll
            for (int j = 0; j < 4; ++j) {
                accs[i][j] *= 0.125f;   // HS^-0.5
                if (st * 64 + sloc + i > q0 + qloc + j) accs[i][j] = -3.0e38f;
            }
        // column max over s (per q)
        float cmax[4];
#pragma unroll
        for (int j = 0; j < 4; ++j)
            cmax[j] = fmaxf(fmaxf(accs[0][j], accs[1][j]), fmaxf(accs[2][j], accs[3][j]));
#pragma unroll
        for (int j = 0; j < 4; ++j) {
            cmax[j] = fmaxf(cmax[j], __shfl_xor(cmax[j], 16));
            cmax[j] = fmaxf(cmax[j], __shfl_xor(cmax[j], 32));
        }
        if ((ty & 3) == 0) {
#pragma unroll
            for (int j = 0; j < 4; ++j) red[wvi][qloc + j] = cmax[j];
        }
        __syncthreads();
        if (tid < 64) {
            float tm = fmaxf(fmaxf(red[0][tid], red[1][tid]), fmaxf(red[2][tid], red[3][tid]));
            float mold = mstate[tid];
            float mnew = fmaxf(mold, tm);
            mnew_s[tid] = mnew;
            rfac[tid] = __expf(mold - mnew);
            mstate[tid] = mnew;
        }
        __syncthreads();
        // P = exp(S - mnew), write P^T to LDS, column sums
        float csum[4] = {0.f, 0.f, 0.f, 0.f};
#pragma unroll
        for (int j = 0; j < 4; ++j) {
            const float mn = mnew_s[qloc + j];
#pragma unroll
            for (int i = 0; i < 4; ++i) {
                float p = __expf(accs[i][j] - mn);
                Pt[sloc + i][qloc + j] = p;
                csum[j] += p;
            }
        }
#pragma unroll
        for (int j = 0; j < 4; ++j) {
            csum[j] += __shfl_xor(csum[j], 16);
            csum[j] += __shfl_xor(csum[j], 32);
        }
        if ((ty & 3) == 0) {
#pragma unroll
            for (int j = 0; j < 4; ++j) red2[wvi][qloc + j] = csum[j];
        }
        __syncthreads();
        if (tid < 64)
            lstate[tid] = lstate[tid] * rfac[tid] + (red2[0][tid] + red2[1][tid] + red2[2][tid] + red2[3][tid]);
        // O rescale + O += P^T * V
#pragma unroll
        for (int i = 0; i < 4; ++i) {
            const float r = rfac[sloc + i];     // sloc == ty*4: q index in O mapping
#pragma unroll
            for (int j = 0; j < 4; ++j) acc_o[i][j] *= r;
        }
#pragma unroll 8
        for (int ssi = 0; ssi < 64; ++ssi) {
            const f32x4 av = *(const f32x4*)&Pt[ssi][ty << 2];
            const f32x4 bv = *(const f32x4*)&Vs[ssi][tx << 2];
#pragma unroll
            for (int i = 0; i < 4; ++i)
#pragma unroll
                for (int j = 0; j < 4; ++j) acc_o[i][j] = fmaf(av[i], bv[j], acc_o[i][j]);
        }
    }
    __syncthreads();
    {   // write O: q = ty*4+i, d = tx*4+j
        const int qrow = ty << 2;
#pragma unroll
        for (int i = 0; i < 4; ++i) {
            const float invl = 1.0f / lstate[qrow + i];
            ushort4 pk;
            pk.x = f2bf(acc_o[i][0] * invl);
            pk.y = f2bf(acc_o[i][1] * invl);
            pk.z = f2bf(acc_o[i][2] * invl);
            pk.w = f2bf(acc_o[i][3] * invl);
            *(ushort4*)(ob + (size_t)(b * NT + q0 + qrow + i) * ND + h * 64 + (tx << 2)) = pk;
        }
    }
}

// ---------------- per-row loss: lse - logit[target] ----------------
__global__ __launch_bounds__(256) void k_rowloss(const float* __restrict__ logits,
                                                 const int* __restrict__ targets,
                                                 float* __restrict__ rl) {
    int m = blockIdx.x;
    const float* row = logits + (size_t)m * NV;
    int tid = threadIdx.x;
    int lane = tid & 63, w = tid >> 6;
    float mx = -INFINITY;
    for (int j = tid; j < NV; j += 256) mx = fmaxf(mx, row[j]);
#pragma unroll
    for (int off = 32; off >= 1; off >>= 1) mx = fmaxf(mx, __shfl_xor(mx, off, 64));
    __shared__ float sm[4];
    if (lane == 0) sm[w] = mx;
    __syncthreads();
    mx = fmaxf(fmaxf(sm[0], sm[1]), fmaxf(sm[2], sm[3]));
    float s = 0.f;
    for (int j = tid; j < NV; j += 256) s += __expf(row[j] - mx);
    s = wave_reduce_sum(s);
    __shared__ float sv[4];
    if (lane == 0) sv[w] = s;
    __syncthreads();
    s = sv[0] + sv[1] + sv[2] + sv[3];
    if (tid == 0) {
        float lse = logf(s) + mx;
        rl[m] = lse - row[targets[m]];
    }
}

__global__ __launch_bounds__(256) void k_lossreduce(const float* __restrict__ rl,
                                                    float* __restrict__ out_loss) {
    int tid = threadIdx.x;
    float s = 0.f;
    for (int j = tid; j < NM; j += 256) s += rl[j];
    s = wave_reduce_sum(s);
    __shared__ float sv[4];
    int lane = tid & 63, w = tid >> 6;
    if (lane == 0) sv[w] = s;
    __syncthreads();
    if (tid == 0) out_loss[0] = (sv[0] + sv[1] + sv[2] + sv[3]) * (1.0f / NM);
}

extern "C" void kernel_launch(void* const* d_in, const int* in_sizes, int n_in,
                              void* d_out, int out_size, void* d_ws, size_t ws_size,
                              hipStream_t stream) {
    const int* idx      = (const int*)d_in[0];
    const int* targets  = (const int*)d_in[1];
    const float* tok    = (const float*)d_in[2];
    const float* pos    = (const float*)d_in[3];
    const float* wq     = (const float*)d_in[4];
    const float* wk     = (const float*)d_in[5];
    const float* wv     = (const float*)d_in[6];
    const float* wproj  = (const float*)d_in[7];
    const float* bproj  = (const float*)d_in[8];
    const float* ln1_g  = (const float*)d_in[9];
    const float* ln1_b  = (const float*)d_in[10];
    const float* ln2_g  = (const float*)d_in[11];
    const float* ln2_b  = (const float*)d_in[12];
    const float* w1     = (const float*)d_in[13];
    const float* b1     = (const float*)d_in[14];
    const float* w2     = (const float*)d_in[15];
    const float* b2     = (const float*)d_in[16];
    const float* lnf_g  = (const float*)d_in[17];
    const float* lnf_b  = (const float*)d_in[18];
    const float* lm_w   = (const float*)d_in[19];
    const float* lm_b   = (const float*)d_in[20];
    float* out = (float*)d_out;

    // workspace carve-up (256B aligned)
    char* wsb = (char*)d_ws;
    auto alloc = [&](size_t bytes) { char* p = wsb; wsb += (bytes + 255) & ~(size_t)255; return p; };
    float* x     = (float*)alloc((size_t)NM * ND * 4);
    u16* h_bf    = (u16*)  alloc((size_t)NM * ND * 2);
    u16* qkv_bf  = (u16*)  alloc((size_t)NM * 3 * ND * 2);
    u16* ob_bf   = (u16*)  alloc((size_t)NM * ND * 2);
    u16* hid_bf  = (u16*)  alloc((size_t)NM * NF * 2);
    float* rl    = (float*)alloc((size_t)NM * 4);
    u16* wqkv_t  = (u16*)  alloc((size_t)3 * ND * ND * 2);
    u16* wp_t    = (u16*)  alloc((size_t)ND * ND * 2);
    u16* w1_t    = (u16*)  alloc((size_t)NF * ND * 2);
    u16* w2_t    = (u16*)  alloc((size_t)ND * NF * 2);
    u16* lm_t    = (u16*)  alloc((size_t)NVPAD * ND * 2);

    k_embed<<<NM, 256, 0, stream>>>(idx, tok, pos, x);
    // LM head weight: transpose+convert once per launch
    k_wtrans<<<dim3(NVPAD / 32, ND / 32), 256, 0, stream>>>(lm_w, lm_t, ND, NV, NVPAD, NV, NV);

    for (int l = 0; l < NL; ++l) {
        const float* wq_l = wq + (size_t)l * NH * ND * 64;
        const float* wk_l = wk + (size_t)l * NH * ND * 64;
        const float* wv_l = wv + (size_t)l * NH * ND * 64;
        const float* wp_l = wproj + (size_t)l * ND * ND;
        const float* bp_l = bproj + (size_t)l * ND;
        const float* w1_l = w1 + (size_t)l * ND * NF;
        const float* b1_l = b1 + (size_t)l * NF;
        const float* w2_l = w2 + (size_t)l * NF * ND;
        const float* b2_l = b2 + (size_t)l * ND;

        k_layernorm<true><<<NM, 256, 0, stream>>>(x, ln1_g + (size_t)l * ND, ln1_b + (size_t)l * ND, nullptr, h_bf);

        // build fused QKV B^T [3072][1024]
        k_wtrans<<<dim3(ND / 32, ND / 32), 256, 0, stream>>>(wq_l, wqkv_t,                 ND, ND, ND, 64, 64);
        k_wtrans<<<dim3(ND / 32, ND / 32), 256, 0, stream>>>(wk_l, wqkv_t + (size_t)ND * ND,     ND, ND, ND, 64, 64);
        k_wtrans<<<dim3(ND / 32, ND / 32), 256, 0, stream>>>(wv_l, wqkv_t + (size_t)2 * ND * ND, ND, ND, ND, 64, 64);
        k_mfma_gemm<false, false, false, true><<<dim3(3 * ND / 128, NM / 128), 256, 0, stream>>>(
            h_bf, wqkv_t, nullptr, nullptr, nullptr, qkv_bf, ND, 3 * ND, 3 * ND);

        k_attn_flash<<<dim3(NT / 64, NB * NH), 256, 0, stream>>>(qkv_bf, ob_bf);

        k_wtrans<<<dim3(ND / 32, ND / 32), 256, 0, stream>>>(wp_l, wp_t, ND, ND, ND, ND, ND);
        k_mfma_gemm<false, true, false, false><<<dim3(ND / 128, NM / 128), 256, 0, stream>>>(
            ob_bf, wp_t, bp_l, x, x, nullptr, ND, ND, ND);

        k_layernorm<true><<<NM, 256, 0, stream>>>(x, ln2_g + (size_t)l * ND, ln2_b + (size_t)l * ND, nullptr, h_bf);

        k_wtrans<<<dim3(NF / 32, ND / 32), 256, 0, stream>>>(w1_l, w1_t, ND, NF, NF, NF, NF);
        k_mfma_gemm<true, false, false, true><<<dim3(NF / 128, NM / 128), 256, 0, stream>>>(
            h_bf, w1_t, b1_l, nullptr, nullptr, hid_bf, ND, NF, NF);

        k_wtrans<<<dim3(ND / 32, NF / 32), 256, 0, stream>>>(w2_l, w2_t, NF, ND, ND, ND, ND);
        k_mfma_gemm<false, true, false, false><<<dim3(ND / 128, NM / 128), 256, 0, stream>>>(
            hid_bf, w2_t, b2_l, x, x, nullptr, NF, ND, ND);
    }

    k_layernorm<true><<<NM, 256, 0, stream>>>(x, lnf_g, lnf_b, nullptr, h_bf);

    k_mfma_gemm<false, false, true, false><<<dim3(NVPAD / 128, NM / 128), 256, 0, stream>>>(
        h_bf, lm_t, lm_b, nullptr, out, nullptr, ND, NV, NV);

    k_rowloss<<<NM, 256, 0, stream>>>(out, targets, rl);
    k_lossreduce<<<1, 256, 0, stream>>>(rl, out + (size_t)NM * NV);
}

// Round 3
// 2331.166 us; speedup vs baseline: 6.9840x; 1.1795x over previous
//
#include <hip/hip_runtime.h>
#include <cstdint>
#include <cstddef>

typedef unsigned short u16;
typedef unsigned int u32;
typedef __bf16 bf16x8 __attribute__((ext_vector_type(8)));
typedef float f32x4 __attribute__((ext_vector_type(4)));
typedef short short8_t __attribute__((ext_vector_type(8)));

#define NV 50257
#define NVPAD 50304   // 393 * 128
#define ND 1024
#define NT 1024
#define NH 16
#define NL 6
#define NB 2
#define NM 2048       // B*T
#define NF 4096       // 4*D
#define EPSLN 1e-5f

__device__ __forceinline__ u16 f2bf(float f) {
    unsigned u = __float_as_uint(f);
    return (u16)((u + 0x7fffu + ((u >> 16) & 1u)) >> 16);   // RNE
}
__device__ __forceinline__ float bf2f(u16 h) {
    return __uint_as_float(((unsigned)h) << 16);
}
__device__ __forceinline__ u32 pack2bf(float lo, float hi) {
    return (u32)f2bf(lo) | ((u32)f2bf(hi) << 16);
}

__device__ __forceinline__ void gload_lds16(const u16* g, u16* l) {
    __builtin_amdgcn_global_load_lds((const __attribute__((address_space(1))) void*)g,
                                     (__attribute__((address_space(3))) void*)l, 16, 0, 0);
}

__device__ __forceinline__ float wave_reduce_sum(float v) {
#pragma unroll
    for (int off = 32; off >= 1; off >>= 1) v += __shfl_xor(v, off, 64);
    return v;
}

// ---------------- embedding ----------------
__global__ __launch_bounds__(256) void k_embed(const int* __restrict__ idx,
                                               const float* __restrict__ tok,
                                               const float* __restrict__ pos,
                                               float* __restrict__ x) {
    int m = blockIdx.x;
    int t = m & (NT - 1);
    int tokid = idx[m];
    int d = threadIdx.x * 4;
    float4 a = *(const float4*)(tok + (size_t)tokid * ND + d);
    float4 p = *(const float4*)(pos + (size_t)t * ND + d);
    a.x += p.x; a.y += p.y; a.z += p.z; a.w += p.w;
    *(float4*)(x + (size_t)m * ND + d) = a;
}

// ---------------- layernorm ----------------
template <bool OUTBF16>
__global__ __launch_bounds__(256) void k_layernorm(const float* __restrict__ x,
                                                   const float* __restrict__ g,
                                                   const float* __restrict__ b,
                                                   float* __restrict__ outf,
                                                   u16* __restrict__ outb) {
    int m = blockIdx.x;
    int d = threadIdx.x * 4;
    const float4 v = *(const float4*)(x + (size_t)m * ND + d);
    float s = v.x + v.y + v.z + v.w;
    float q = v.x * v.x + v.y * v.y + v.z * v.z + v.w * v.w;
    s = wave_reduce_sum(s);
    q = wave_reduce_sum(q);
    __shared__ float ss[4], sq[4];
    int lane = threadIdx.x & 63, w = threadIdx.x >> 6;
    if (lane == 0) { ss[w] = s; sq[w] = q; }
    __syncthreads();
    s = ss[0] + ss[1] + ss[2] + ss[3];
    q = sq[0] + sq[1] + sq[2] + sq[3];
    float mu = s * (1.0f / ND);
    float var = q * (1.0f / ND) - mu * mu;
    float rstd = rsqrtf(var + EPSLN);
    float4 gg = *(const float4*)(g + d);
    float4 bb = *(const float4*)(b + d);
    float o0 = (v.x - mu) * rstd * gg.x + bb.x;
    float o1 = (v.y - mu) * rstd * gg.y + bb.y;
    float o2 = (v.z - mu) * rstd * gg.z + bb.z;
    float o3 = (v.w - mu) * rstd * gg.w + bb.w;
    if (OUTBF16) {
        ushort4 pk;
        pk.x = f2bf(o0); pk.y = f2bf(o1); pk.z = f2bf(o2); pk.w = f2bf(o3);
        *(ushort4*)(outb + (size_t)m * ND + d) = pk;
    } else {
        float4 o; o.x = o0; o.y = o1; o.z = o2; o.w = o3;
        *(float4*)(outf + (size_t)m * ND + d) = o;
    }
}

// ---------------- weight transpose + f32->bf16 ----------------
__global__ __launch_bounds__(256) void k_wtrans(const float* __restrict__ W,
                                                u16* __restrict__ Wt,
                                                int K, int N, int Npad, int hs, int ld) {
    __shared__ float t[32][33];
    const int nb = blockIdx.x << 5, kb = blockIdx.y << 5;
    const int tx = threadIdx.x & 31, tq = threadIdx.x >> 5;
    const int n = nb + tx;
    if (n < N) {
        const int head = n / hs, nc = n - head * hs;
        const float* src = W + (size_t)head * K * hs + nc;
#pragma unroll
        for (int i = 0; i < 4; ++i)
            t[(tq << 2) + i][tx] = src[(size_t)(kb + (tq << 2) + i) * ld];
    } else {
#pragma unroll
        for (int i = 0; i < 4; ++i) t[(tq << 2) + i][tx] = 0.f;
    }
    __syncthreads();
#pragma unroll
    for (int i = 0; i < 4; ++i) {
        const int nn = nb + (tq << 2) + i;
        if (nn < Npad) Wt[(size_t)nn * K + kb + tx] = f2bf(t[tx][(tq << 2) + i]);
    }
}

// ---------------- V transpose: qkv[B,T,3072] -> vt[B,H,64,T] (bf16) ----------------
__global__ __launch_bounds__(256) void k_vtrans(const u16* __restrict__ qkv,
                                                u16* __restrict__ vt) {
    __shared__ u16 L[64][72];
    const int tt = blockIdx.x, bh = blockIdx.y;
    const int b = bh >> 4, h = bh & 15;
    const int tid = threadIdx.x;
    const int tr = tid >> 2, dc = (tid & 3) << 4;
    const u16* src = qkv + (size_t)(b * NT + tt * 64 + tr) * 3072 + 2048 + h * 64 + dc;
    short8_t v0 = *(const short8_t*)src;
    short8_t v1 = *(const short8_t*)(src + 8);
#pragma unroll
    for (int j = 0; j < 8; ++j) { L[tr][dc + j] = (u16)v0[j]; L[tr][dc + 8 + j] = (u16)v1[j]; }
    __syncthreads();
    const int dr = tid >> 2, tc = (tid & 3) << 4;
    union { u16 us[16]; short8_t v[2]; } tmp;
#pragma unroll
    for (int j = 0; j < 16; ++j) tmp.us[j] = L[tc + j][dr];
    u16* dst = vt + ((size_t)bh * 64 + dr) * NT + tt * 64 + tc;
    *(short8_t*)dst = tmp.v[0];
    *(short8_t*)(dst + 8) = tmp.v[1];
}

// ---------------- bf16 MFMA GEMM (global_load_lds, dbuf, 1 barrier/K-step) ----------
// 128x128 tile, BK=32, 4 waves (2x2). Grid = (16 m-tiles, nTiles); m-fastest + XCD swz.
// LDS [128][32] u16, 16B-chunk XOR swizzle: slot = chunk ^ (row&3), via pre-swizzled src.
template <bool RELU, bool RESID, bool NBOUND, bool OUTBF16>
__global__ __launch_bounds__(256) void k_mfma_gemm(
    const u16* __restrict__ A, const u16* __restrict__ Bt,
    const float* __restrict__ bias, const float* __restrict__ resid,
    float* __restrict__ Cf, u16* __restrict__ Cb,
    int K, int N, int ldc)
{
    __shared__ u16 As[2][128 * 32];
    __shared__ u16 Bs[2][128 * 32];
    const int lin = blockIdx.y * 16 + blockIdx.x;
    const int nwg = (int)gridDim.y * 16;         // % 8 == 0 for all our shapes
    const int cpx = nwg >> 3;
    const int swz = (lin & 7) * cpx + (lin >> 3);
    const int m0 = (swz & 15) * 128;
    const int n0 = (swz >> 4) * 128;
    const int tid = threadIdx.x;
    const int lane = tid & 63, wv = tid >> 6;
    const int wr = wv >> 1, wc = wv & 1;
    const int lr = lane & 15, kg = lane >> 4;

    // staging: issue i in {0,1}: LDS rows (i*64) + wv*16 + (lane>>2), slot lane&3
    const int srow = lane >> 2;
    const int scol = (((lane & 3) ^ (srow & 3)) << 3);   // pre-swizzled source chunk
    const u16* gA0 = A + (size_t)(m0 + wv * 16 + srow) * K + scol;
    const u16* gA1 = gA0 + (size_t)64 * K;
    const u16* gB0 = Bt + (size_t)(n0 + wv * 16 + srow) * K + scol;
    const u16* gB1 = gB0 + (size_t)64 * K;

    f32x4 acc[4][4] = {};
    const int nt = K >> 5;

    gload_lds16(gA0, &As[0][wv * 512]);
    gload_lds16(gA1, &As[0][2048 + wv * 512]);
    gload_lds16(gB0, &Bs[0][wv * 512]);
    gload_lds16(gB1, &Bs[0][2048 + wv * 512]);
    __syncthreads();

    int cur = 0;
    for (int t = 0; t < nt; ++t) {
        if (t + 1 < nt) {
            const int ko = (t + 1) << 5;
            gload_lds16(gA0 + ko, &As[cur ^ 1][wv * 512]);
            gload_lds16(gA1 + ko, &As[cur ^ 1][2048 + wv * 512]);
            gload_lds16(gB0 + ko, &Bs[cur ^ 1][wv * 512]);
            gload_lds16(gB1 + ko, &Bs[cur ^ 1][2048 + wv * 512]);
        }
        bf16x8 af[4], bfr[4];
#pragma unroll
        for (int mi = 0; mi < 4; ++mi) {
            const int R = wr * 64 + mi * 16 + lr;
            af[mi] = *(const bf16x8*)&As[cur][R * 32 + ((kg ^ (R & 3)) << 3)];
        }
#pragma unroll
        for (int ni = 0; ni < 4; ++ni) {
            const int R = wc * 64 + ni * 16 + lr;
            bfr[ni] = *(const bf16x8*)&Bs[cur][R * 32 + ((kg ^ (R & 3)) << 3)];
        }
#pragma unroll
        for (int mi = 0; mi < 4; ++mi)
#pragma unroll
            for (int ni = 0; ni < 4; ++ni)
                acc[mi][ni] = __builtin_amdgcn_mfma_f32_16x16x32_bf16(af[mi], bfr[ni], acc[mi][ni], 0, 0, 0);
        __syncthreads();
        cur ^= 1;
    }
#pragma unroll
    for (int mi = 0; mi < 4; ++mi) {
#pragma unroll
        for (int ni = 0; ni < 4; ++ni) {
#pragma unroll
            for (int r = 0; r < 4; ++r) {
                const int row = m0 + wr * 64 + mi * 16 + kg * 4 + r;
                const int col = n0 + wc * 64 + ni * 16 + lr;
                if (NBOUND && col >= N) continue;
                float c = acc[mi][ni][r];
                if (bias) c += bias[col];
                if (RELU) c = fmaxf(c, 0.f);
                if (RESID) c += resid[(size_t)row * ldc + col];
                if (OUTBF16) Cb[(size_t)row * ldc + col] = f2bf(c);
                else         Cf[(size_t)row * ldc + col] = c;
            }
        }
    }
}

// ---------------- MFMA flash attention ----------------
// Block: (q-tile 64, b*H+h), 4 waves; wave w owns q rows [qt*64+w*16, +16).
// S^T = mfma(K, Q): lane holds P[q=lr][s = mi*16+kg*4+r]  (16 f32, q fixed per lane).
// PV = mfma(P, Vt): P A-frags built via 16 shuffles; V staged d-major from vt.
// LDS tiles [64][64] u16, 16B-chunk XOR swizzle: slot = chunk ^ (row&7).
__global__ __launch_bounds__(256) void k_attn_mfma(const u16* __restrict__ qkv,
                                                   const u16* __restrict__ vt,
                                                   u16* __restrict__ ob) {
    const int qt = blockIdx.x, bh = blockIdx.y;
    const int b = bh >> 4, h = bh & 15;
    const int tid = threadIdx.x;
    const int lane = tid & 63, w = tid >> 6;
    const int lr = lane & 15, kg = lane >> 4;

    __shared__ u16 Qs[64 * 64];
    __shared__ u16 Ks[2][64 * 64];
    __shared__ u16 Vs[2][64 * 64];

    const int srow8 = lane >> 3;                 // 0..7
    const int csw = ((lane & 7) ^ srow8) << 3;   // pre-swizzled source chunk (elems)

    {   // stage Q once: rows w*8+srow8 (i0), +32 (i1)
        const int r0 = w * 8 + srow8;
        gload_lds16(qkv + (size_t)(b * NT + qt * 64 + r0) * 3072 + h * 64 + csw, &Qs[w * 512]);
        gload_lds16(qkv + (size_t)(b * NT + qt * 64 + 32 + r0) * 3072 + h * 64 + csw, &Qs[2048 + w * 512]);
    }
#define STAGE_KV(bb, st)                                                                            \
    {                                                                                               \
        const int r0_ = w * 8 + srow8;                                                              \
        gload_lds16(qkv + (size_t)(b * NT + (st) * 64 + r0_) * 3072 + 1024 + h * 64 + csw,          \
                    &Ks[bb][w * 512]);                                                              \
        gload_lds16(qkv + (size_t)(b * NT + (st) * 64 + 32 + r0_) * 3072 + 1024 + h * 64 + csw,     \
                    &Ks[bb][2048 + w * 512]);                                                       \
        gload_lds16(vt + ((size_t)bh * 64 + r0_) * NT + (st) * 64 + csw, &Vs[bb][w * 512]);         \
        gload_lds16(vt + ((size_t)bh * 64 + 32 + r0_) * NT + (st) * 64 + csw,                       \
                    &Vs[bb][2048 + w * 512]);                                                       \
    }
    STAGE_KV(0, 0);
    __syncthreads();

    // Q B-frags (read once, keep in regs)
    bf16x8 qf[2];
    {
        const int qrow = w * 16 + lr;
#pragma unroll
        for (int ds_ = 0; ds_ < 2; ++ds_)
            qf[ds_] = *(const bf16x8*)&Qs[qrow * 64 + ((((ds_ << 2) + kg) ^ (lr & 7)) << 3)];
    }

    float mstate = -3.0e38f, lstate = 0.f;
    f32x4 acc_o[4] = {};
    const int qg = qt * 64 + w * 16 + lr;

    int cur = 0;
    for (int st = 0; st <= qt; ++st) {
        if (st < qt) STAGE_KV(cur ^ 1, st + 1);
        const bool diag = (st == qt);
        const int milim = diag ? w : 3;

        f32x4 acc_s[4] = {};
#pragma unroll
        for (int mi = 0; mi < 4; ++mi) {
            if (mi <= milim) {
                const int srw = mi * 16 + lr;
#pragma unroll
                for (int ds_ = 0; ds_ < 2; ++ds_) {
                    bf16x8 kf = *(const bf16x8*)&Ks[cur][srw * 64 + ((((ds_ << 2) + kg) ^ (lr & 7)) << 3)];
                    acc_s[mi] = __builtin_amdgcn_mfma_f32_16x16x32_bf16(kf, qf[ds_], acc_s[mi], 0, 0, 0);
                }
            }
        }
        // mask + scale; per-lane row state (q = lr)
        float tilemax = -3.0e38f;
#pragma unroll
        for (int mi = 0; mi < 4; ++mi)
#pragma unroll
            for (int r = 0; r < 4; ++r) {
                float x_ = acc_s[mi][r] * 0.125f;
                const int sg = st * 64 + mi * 16 + kg * 4 + r;
                if (mi > milim || sg > qg) x_ = -3.0e38f;
                acc_s[mi][r] = x_;
                tilemax = fmaxf(tilemax, x_);
            }
        tilemax = fmaxf(tilemax, __shfl_xor(tilemax, 16));
        tilemax = fmaxf(tilemax, __shfl_xor(tilemax, 32));
        const float mnew = fmaxf(mstate, tilemax);
        const float rfac = __expf(mstate - mnew);
        mstate = mnew;

        float psum = 0.f;
        u32 pk[4][2];
#pragma unroll
        for (int mi = 0; mi < 4; ++mi) {
            float p0 = __expf(acc_s[mi][0] - mnew);
            float p1 = __expf(acc_s[mi][1] - mnew);
            float p2 = __expf(acc_s[mi][2] - mnew);
            float p3 = __expf(acc_s[mi][3] - mnew);
            psum += p0 + p1 + p2 + p3;
            pk[mi][0] = pack2bf(p0, p1);
            pk[mi][1] = pack2bf(p2, p3);
        }
        psum += __shfl_xor(psum, 16);
        psum += __shfl_xor(psum, 32);
        lstate = lstate * rfac + psum;

        // rescale O (rows q_loc = kg*4+r; state lives in lane lr = q_loc, kg-group 0)
        float rf[4];
#pragma unroll
        for (int r = 0; r < 4; ++r) rf[r] = __shfl(rfac, kg * 4 + r);
#pragma unroll
        for (int ni = 0; ni < 4; ++ni)
#pragma unroll
            for (int r = 0; r < 4; ++r) acc_o[ni][r] *= rf[r];

        // P A-frags via shuffles + PV
        const int src0 = ((kg & 1) << 5) + lr;   // ((kg&1)*2)*16 + lr
        const int src1 = src0 + 16;
#pragma unroll
        for (int ks_ = 0; ks_ < 2; ++ks_) {
            const u32 lo_a = __shfl((int)pk[ks_ * 2][0], src0);
            const u32 lo_b = __shfl((int)pk[ks_ * 2][1], src0);
            const u32 lo_c = __shfl((int)pk[ks_ * 2][0], src1);
            const u32 lo_d = __shfl((int)pk[ks_ * 2][1], src1);
            const u32 hi_a = __shfl((int)pk[ks_ * 2 + 1][0], src0);
            const u32 hi_b = __shfl((int)pk[ks_ * 2 + 1][1], src0);
            const u32 hi_c = __shfl((int)pk[ks_ * 2 + 1][0], src1);
            const u32 hi_d = __shfl((int)pk[ks_ * 2 + 1][1], src1);
            union { u32 u[4]; bf16x8 v; } pa;
            pa.u[0] = (kg & 2) ? hi_a : lo_a;
            pa.u[1] = (kg & 2) ? hi_b : lo_b;
            pa.u[2] = (kg & 2) ? hi_c : lo_c;
            pa.u[3] = (kg & 2) ? hi_d : lo_d;
#pragma unroll
            for (int ni = 0; ni < 4; ++ni) {
                const int drow = ni * 16 + lr;
                bf16x8 vf = *(const bf16x8*)&Vs[cur][drow * 64 + ((((ks_ << 2) + kg) ^ (lr & 7)) << 3)];
                acc_o[ni] = __builtin_amdgcn_mfma_f32_16x16x32_bf16(pa.v, vf, acc_o[ni], 0, 0, 0);
            }
        }
        __syncthreads();
        cur ^= 1;
    }

    float il[4];
#pragma unroll
    for (int r = 0; r < 4; ++r) il[r] = 1.0f / __shfl(lstate, kg * 4 + r);
#pragma unroll
    for (int ni = 0; ni < 4; ++ni)
#pragma unroll
        for (int r = 0; r < 4; ++r) {
            const int q2 = qt * 64 + w * 16 + kg * 4 + r;
            ob[(size_t)(b * NT + q2) * ND + h * 64 + ni * 16 + lr] = f2bf(acc_o[ni][r] * il[r]);
        }
#undef STAGE_KV
}

// ---------------- per-row loss ----------------
__global__ __launch_bounds__(256) void k_rowloss(const float* __restrict__ logits,
                                                 const int* __restrict__ targets,
                                                 float* __restrict__ rl) {
    int m = blockIdx.x;
    const float* row = logits + (size_t)m * NV;
    int tid = threadIdx.x;
    int lane = tid & 63, w = tid >> 6;
    float mx = -INFINITY;
    for (int j = tid; j < NV; j += 256) mx = fmaxf(mx, row[j]);
#pragma unroll
    for (int off = 32; off >= 1; off >>= 1) mx = fmaxf(mx, __shfl_xor(mx, off, 64));
    __shared__ float sm[4];
    if (lane == 0) sm[w] = mx;
    __syncthreads();
    mx = fmaxf(fmaxf(sm[0], sm[1]), fmaxf(sm[2], sm[3]));
    float s = 0.f;
    for (int j = tid; j < NV; j += 256) s += __expf(row[j] - mx);
    s = wave_reduce_sum(s);
    __shared__ float sv[4];
    if (lane == 0) sv[w] = s;
    __syncthreads();
    s = sv[0] + sv[1] + sv[2] + sv[3];
    if (tid == 0) {
        float lse = logf(s) + mx;
        rl[m] = lse - row[targets[m]];
    }
}

__global__ __launch_bounds__(256) void k_lossreduce(const float* __restrict__ rl,
                                                    float* __restrict__ out_loss) {
    int tid = threadIdx.x;
    float s = 0.f;
    for (int j = tid; j < NM; j += 256) s += rl[j];
    s = wave_reduce_sum(s);
    __shared__ float sv[4];
    int lane = tid & 63, w = tid >> 6;
    if (lane == 0) sv[w] = s;
    __syncthreads();
    if (tid == 0) out_loss[0] = (sv[0] + sv[1] + sv[2] + sv[3]) * (1.0f / NM);
}

extern "C" void kernel_launch(void* const* d_in, const int* in_sizes, int n_in,
                              void* d_out, int out_size, void* d_ws, size_t ws_size,
                              hipStream_t stream) {
    const int* idx      = (const int*)d_in[0];
    const int* targets  = (const int*)d_in[1];
    const float* tok    = (const float*)d_in[2];
    const float* pos    = (const float*)d_in[3];
    const float* wq     = (const float*)d_in[4];
    const float* wk     = (const float*)d_in[5];
    const float* wv     = (const float*)d_in[6];
    const float* wproj  = (const float*)d_in[7];
    const float* bproj  = (const float*)d_in[8];
    const float* ln1_g  = (const float*)d_in[9];
    const float* ln1_b  = (const float*)d_in[10];
    const float* ln2_g  = (const float*)d_in[11];
    const float* ln2_b  = (const float*)d_in[12];
    const float* w1     = (const float*)d_in[13];
    const float* b1     = (const float*)d_in[14];
    const float* w2     = (const float*)d_in[15];
    const float* b2     = (const float*)d_in[16];
    const float* lnf_g  = (const float*)d_in[17];
    const float* lnf_b  = (const float*)d_in[18];
    const float* lm_w   = (const float*)d_in[19];
    const float* lm_b   = (const float*)d_in[20];
    float* out = (float*)d_out;

    char* wsb = (char*)d_ws;
    auto alloc = [&](size_t bytes) { char* p = wsb; wsb += (bytes + 255) & ~(size_t)255; return p; };
    float* x     = (float*)alloc((size_t)NM * ND * 4);
    u16* h_bf    = (u16*)  alloc((size_t)NM * ND * 2);
    u16* qkv_bf  = (u16*)  alloc((size_t)NM * 3 * ND * 2);
    u16* vt_bf   = (u16*)  alloc((size_t)NB * NH * 64 * NT * 2);
    u16* ob_bf   = (u16*)  alloc((size_t)NM * ND * 2);
    u16* hid_bf  = (u16*)  alloc((size_t)NM * NF * 2);
    float* rl    = (float*)alloc((size_t)NM * 4);
    u16* wqkv_t  = (u16*)  alloc((size_t)3 * ND * ND * 2);
    u16* wp_t    = (u16*)  alloc((size_t)ND * ND * 2);
    u16* w1_t    = (u16*)  alloc((size_t)NF * ND * 2);
    u16* w2_t    = (u16*)  alloc((size_t)ND * NF * 2);
    u16* lm_t    = (u16*)  alloc((size_t)NVPAD * ND * 2);

    k_embed<<<NM, 256, 0, stream>>>(idx, tok, pos, x);
    k_wtrans<<<dim3(NVPAD / 32, ND / 32), 256, 0, stream>>>(lm_w, lm_t, ND, NV, NVPAD, NV, NV);

    for (int l = 0; l < NL; ++l) {
        const float* wq_l = wq + (size_t)l * NH * ND * 64;
        const float* wk_l = wk + (size_t)l * NH * ND * 64;
        const float* wv_l = wv + (size_t)l * NH * ND * 64;
        const float* wp_l = wproj + (size_t)l * ND * ND;
        const float* bp_l = bproj + (size_t)l * ND;
        const float* w1_l = w1 + (size_t)l * ND * NF;
        const float* b1_l = b1 + (size_t)l * NF;
        const float* w2_l = w2 + (size_t)l * NF * ND;
        const float* b2_l = b2 + (size_t)l * ND;

        k_layernorm<true><<<NM, 256, 0, stream>>>(x, ln1_g + (size_t)l * ND, ln1_b + (size_t)l * ND, nullptr, h_bf);

        k_wtrans<<<dim3(ND / 32, ND / 32), 256, 0, stream>>>(wq_l, wqkv_t,                       ND, ND, ND, 64, 64);
        k_wtrans<<<dim3(ND / 32, ND / 32), 256, 0, stream>>>(wk_l, wqkv_t + (size_t)ND * ND,     ND, ND, ND, 64, 64);
        k_wtrans<<<dim3(ND / 32, ND / 32), 256, 0, stream>>>(wv_l, wqkv_t + (size_t)2 * ND * ND, ND, ND, ND, 64, 64);
        k_mfma_gemm<false, false, false, true><<<dim3(16, 24), 256, 0, stream>>>(
            h_bf, wqkv_t, nullptr, nullptr, nullptr, qkv_bf, ND, 3 * ND, 3 * ND);

        k_vtrans<<<dim3(NT / 64, NB * NH), 256, 0, stream>>>(qkv_bf, vt_bf);
        k_attn_mfma<<<dim3(NT / 64, NB * NH), 256, 0, stream>>>(qkv_bf, vt_bf, ob_bf);

        k_wtrans<<<dim3(ND / 32, ND / 32), 256, 0, stream>>>(wp_l, wp_t, ND, ND, ND, ND, ND);
        k_mfma_gemm<false, true, false, false><<<dim3(16, 8), 256, 0, stream>>>(
            ob_bf, wp_t, bp_l, x, x, nullptr, ND, ND, ND);

        k_layernorm<true><<<NM, 256, 0, stream>>>(x, ln2_g + (size_t)l * ND, ln2_b + (size_t)l * ND, nullptr, h_bf);

        k_wtrans<<<dim3(NF / 32, ND / 32), 256, 0, stream>>>(w1_l, w1_t, ND, NF, NF, NF, NF);
        k_mfma_gemm<true, false, false, true><<<dim3(16, 32), 256, 0, stream>>>(
            h_bf, w1_t, b1_l, nullptr, nullptr, hid_bf, ND, NF, NF);

        k_wtrans<<<dim3(ND / 32, NF / 32), 256, 0, stream>>>(w2_l, w2_t, NF, ND, ND, ND, ND);
        k_mfma_gemm<false, true, false, false><<<dim3(16, 8), 256, 0, stream>>>(
            hid_bf, w2_t, b2_l, x, x, nullptr, NF, ND, ND);
    }

    k_layernorm<true><<<NM, 256, 0, stream>>>(x, lnf_g, lnf_b, nullptr, h_bf);

    k_mfma_gemm<false, false, true, false><<<dim3(16, NVPAD / 128), 256, 0, stream>>>(
        h_bf, lm_t, lm_b, nullptr, out, nullptr, ND, NV, NV);

    k_rowloss<<<NM, 256, 0, stream>>>(out, targets, rl);
    k_lossreduce<<<1, 256, 0, stream>>>(rl, out + (size_t)NM * NV);
}